// Round 1
// baseline (75465.112 us; speedup 1.0000x reference)
//
#include <hip/hip_runtime.h>
#include <cmath>

typedef _Float16 f16;
typedef _Float16 f16x8 __attribute__((ext_vector_type(8)));
typedef float f32x4 __attribute__((ext_vector_type(4)));

#define MFMA_F16(a,b,c) __builtin_amdgcn_mfma_f32_16x16x32_f16((a),(b),(c),0,0,0)

// Problem constants
// N=64, A=128, MO=126, LX=96, H=1024, S=32, P=2, B=16, BL=32, T=448
// IN=382 (pad 384), GIN=1406
#define TSTEPS 448
#define OFF_MU 3612672   // 64*126*448
#define OFF_LV 4530176   // + 64*32*448

struct Ptrs {
  const float *aud, *mo, *lxm, *eps;
  const int *vid;
  const float *csi_w0, *csi_b0, *csi_w1, *csi_b1, *csi_w2, *csi_b2;
  const float *spk, *mu_w, *mu_b, *lv_w, *lv_b;
  const float *embW, *embB;
  const float *wih0, *whh0, *bih0, *bhh0;
  const float *wih1, *whh1, *bih1, *bhh1;
  const float *ln_g, *ln_b, *predW, *predB;
  float *out;
  unsigned *bar;
  float *stats, *mu5, *lv5, *h0F, *h1F;
  f16 *h0B, *h1B, *ineB, *xcat;
  float *gh0, *gh1, *gi0p, *x0, *x1, *predsT;
  f16 *whh0P, *whh1P, *wih0aP, *wih0bP, *wih1P, *embWP, *predWP;
};

__device__ __forceinline__ float geluf(float x) {
  return 0.5f * x * (1.0f + erff(x * 0.7071067811865475f));
}
__device__ __forceinline__ float sigmf(float x) {
  return 1.0f / (1.0f + expf(-x));
}

// ---------------- prologue kernels ----------------

__global__ void k_init(Ptrs p) {
  if (threadIdx.x == 0) p.bar[0] = 0u;
  if (threadIdx.x < 128) p.stats[threadIdx.x] = 0.f;
}

// Pack W (rows rowOff..rowOff+K of a (?,ldN) fp32 row-major matrix) into MFMA
// B-fragment tiles: dst[(ct*nkt + kt)*512 + l*8 + i] = W[kt*32+(l>>4)*8+i][ct*16+(l&15)]
__global__ void k_pack(const float* __restrict__ src, f16* __restrict__ dst,
                       int K, int rowOff, int realN, int ldN) {
  int ct = blockIdx.x, kt = blockIdx.y;
  int e = threadIdx.x * 2;
  int l = e >> 3, i = e & 7;
  int k = kt * 32 + (l >> 4) * 8 + i;
  int col = ct * 16 + (l & 15);
  f16 v0 = (f16)0.f, v1 = (f16)0.f;
  if (k < K && col < realN)     v0 = (f16)src[(size_t)(rowOff + k) * ldN + col];
  if (k + 1 < K && col < realN) v1 = (f16)src[(size_t)(rowOff + k + 1) * ldN + col];
  size_t o = ((size_t)ct * gridDim.y + kt) * 512 + e;
  dst[o] = v0; dst[o + 1] = v1;
}

__global__ void k_csi1(Ptrs p) {  // x0 = gelu(cat(mo[:,:,31], lxm[:,:,0]) @ w0 + b0)
  int gid = blockIdx.x * 256 + threadIdx.x;  // 65536
  int n = gid >> 10, c = gid & 1023;
  float acc = p.csi_b0[c];
  const float* w = p.csi_w0 + c;
  for (int k = 0; k < 126; k++) acc += p.mo[((size_t)(n * 126 + k)) * 512 + 31] * w[(size_t)k * 1024];
  for (int k = 0; k < 96; k++)  acc += p.lxm[(size_t)(n * 96 + k) * 16] * w[(size_t)(126 + k) * 1024];
  p.x0[gid] = geluf(acc);
}

__global__ void k_csi2(Ptrs p) {  // x1 = gelu(x0 @ w1 + b1)
  int gid = blockIdx.x * 256 + threadIdx.x;
  int n = gid >> 10, c = gid & 1023;
  float acc = p.csi_b1[c];
  const float* w = p.csi_w1 + c;
  const float* x = p.x0 + (size_t)n * 1024;
  for (int k = 0; k < 1024; k++) acc += x[k] * w[(size_t)k * 1024];
  p.x1[gid] = geluf(acc);
}

__global__ void k_csi3(Ptrs p) {  // cell = x1 @ w2 + b2 -> h0, h1
  int gid = blockIdx.x * 256 + threadIdx.x;  // 131072
  int n = gid >> 11, c2 = gid & 2047;
  float acc = p.csi_b2[c2];
  const float* w = p.csi_w2 + c2;
  const float* x = p.x1 + (size_t)n * 1024;
  for (int k = 0; k < 1024; k++) acc += x[k] * w[(size_t)k * 2048];
  if (c2 < 1024) { p.h0F[n * 1024 + c2] = acc; p.h0B[n * 1024 + c2] = (f16)acc; }
  else           { p.h1F[n * 1024 + c2 - 1024] = acc; p.h1B[n * 1024 + c2 - 1024] = (f16)acc; }
}

__global__ void k_style1(Ptrs p) {  // mu5/lv5 = spk_emb @ {mu,lv}_w + b  (5x32)
  int tid = threadIdx.x;
  if (tid < 160) {
    int v = tid >> 5, s = tid & 31;
    float m = p.mu_b[s], lv = p.lv_b[s];
    for (int k = 0; k < 32; k++) {
      float z = p.spk[v * 32 + k];
      m += z * p.mu_w[k * 32 + s];
      lv += z * p.lv_w[k * 32 + s];
    }
    p.mu5[v * 32 + s] = m; p.lv5[v * 32 + s] = lv;
  }
}

__global__ void k_style2(Ptrs p) {  // z_mu/z_lv outputs + style section of xcat
  int gid = blockIdx.x * 256 + threadIdx.x;  // 917504 = 64*32*448
  int t = gid % 448;
  int rr = gid / 448;
  int s = rr & 31, n = rr >> 5;
  int v = p.vid[n * 16 + (t >> 5) + 1];
  float mu = p.mu5[v * 32 + s], lv = p.lv5[v * 32 + s];
  float e = p.eps[((size_t)t * 64 + n) * 32 + s];
  float st = mu + e * expf(0.5f * lv);
  p.out[OFF_MU + ((size_t)n * 32 + s) * 448 + t] = mu;
  p.out[OFF_LV + ((size_t)n * 32 + s) * 448 + t] = lv;
  p.xcat[((size_t)t * 64 + n) * 384 + 350 + s] = (f16)st;
}

__global__ void k_aud(Ptrs p) {  // aud section of xcat (transpose via LDS)
  __shared__ float tile[32][65];
  int bid = blockIdx.x;  // 64*4*7
  int n = bid / 28, rem = bid % 28;
  int a0 = (rem / 7) * 32, t0 = (rem % 7) * 64;
  int tid = threadIdx.x;
  for (int i = tid; i < 2048; i += 256) {
    int ai = i >> 6, tj = i & 63;
    tile[ai][tj] = p.aud[((size_t)n * 128 + a0 + ai) * 448 + t0 + tj];
  }
  __syncthreads();
  for (int i = tid; i < 2048; i += 256) {
    int tj = i >> 5, ai = i & 31;
    p.xcat[((size_t)(t0 + tj) * 64 + n) * 384 + 126 + a0 + ai] = (f16)tile[ai][tj];
  }
}

__global__ void k_lxm(Ptrs p) {  // lxm section of xcat
  int gid = blockIdx.x * 256 + threadIdx.x;  // 2752512 = 448*64*96
  int l_ = gid % 96;
  int r = gid / 96;
  int n = r & 63, t = r >> 6;
  int tb = (t >> 5) + 1;
  p.xcat[((size_t)t * 64 + n) * 384 + 254 + l_] = (f16)p.lxm[((size_t)n * 96 + l_) * 16 + tb];
}

__global__ void k_premo0(Ptrs p) {  // premo init = mo[:,:,31]
  int gid = blockIdx.x * 256 + threadIdx.x;
  if (gid < 8064) {
    int n = gid / 126, m = gid % 126;
    p.xcat[(size_t)n * 384 + m] = (f16)p.mo[((size_t)n * 126 + m) * 512 + 31];
  }
}

// ---------------- persistent scan kernel ----------------

__device__ __forceinline__ void gbar(unsigned* bar, unsigned& epoch) {
  __syncthreads();
  if (threadIdx.x == 0) {
    __threadfence();
    __hip_atomic_fetch_add(bar, 1u, __ATOMIC_RELAXED, __HIP_MEMORY_SCOPE_AGENT);
    unsigned tgt = (epoch + 1u) * 256u;
    while (__hip_atomic_load(bar, __ATOMIC_RELAXED, __HIP_MEMORY_SCOPE_AGENT) < tgt) {
      __builtin_amdgcn_s_sleep(2);
    }
  }
  __syncthreads();
  __threadfence();
  epoch++;
}

__global__ __launch_bounds__(256, 1) void k_scan(Ptrs p) {
  extern __shared__ char smem[];
  f16* actS   = (f16*)smem;                       // 16 x 1032 f16 = 33024 B
  f16* bS     = (f16*)(smem + 33024);             // 49152 f16 = 98304 B
  float* gateS = (float*)(smem + 33024 + 98304);  // 1024 f32 = 4096 B
  float* trS   = (float*)(smem + 135424);         // 272 f32 = 1088 B

  const int b = blockIdx.x, tid = threadIdx.x;
  const int w = tid >> 6, l = tid & 63;
  const int lm = l & 15, lq = l >> 4;
  unsigned epoch = 0;

  for (int t = 0; t < TSTEPS; t++) {
    const f16* xc = p.xcat + (size_t)t * 24576;

    // ======== PHASE A: gh0, gh1, gi0p (= xcat@wih0b + bih0), ine ========
    for (int pr = b; pr < 320; pr += 256) {
      const f16 *act, *wp; const float *bias; float *outF; int nkt, ld, ct0, type;
      if (pr < 96)       { act = p.h0B; wp = p.whh0P;  bias = p.bhh0; nkt = 32; ld = 1024; ct0 = 2 * pr;         type = 0; outF = p.gh0; }
      else if (pr < 192) { act = p.h1B; wp = p.whh1P;  bias = p.bhh1; nkt = 32; ld = 1024; ct0 = 2 * (pr - 96);  type = 0; outF = p.gh1; }
      else if (pr < 288) { act = xc;    wp = p.wih0bP; bias = p.bih0; nkt = 12; ld = 384;  ct0 = 2 * (pr - 192); type = 0; outF = p.gi0p; }
      else               { act = xc;    wp = p.embWP;  bias = p.embB; nkt = 12; ld = 384;  ct0 = 2 * (pr - 288); type = 1; outF = nullptr; }

      {  // stage this pair's packed weights into LDS (contiguous, <= 64 KB)
        const uint4* wsrc = (const uint4*)(wp + (size_t)ct0 * nkt * 512);
        int n4 = nkt * 128;
        uint4* d4 = (uint4*)bS;
        for (int i = tid; i < n4; i += 256) d4[i] = wsrc[i];
      }
      __syncthreads();

      f32x4 acc0 = {0.f, 0.f, 0.f, 0.f}, acc1 = {0.f, 0.f, 0.f, 0.f};
      {
        const f16* aB = act + (size_t)(w * 16 + lm) * ld + lq * 8;
        const f16* b0 = bS + l * 8;
        const f16* b1 = bS + (size_t)nkt * 512 + l * 8;
        f16x8 a0 = *(const f16x8*)(aB);
        f16x8 a1 = *(const f16x8*)(aB + 32);
        for (int kt = 0; kt < nkt; kt += 2) {
          f16x8 na0 = a0, na1 = a1;
          if (kt + 2 < nkt) {
            na0 = *(const f16x8*)(aB + (kt + 2) * 32);
            na1 = *(const f16x8*)(aB + (kt + 3) * 32);
          }
          f16x8 w00 = *(const f16x8*)(b0 + kt * 512);
          f16x8 w10 = *(const f16x8*)(b1 + kt * 512);
          f16x8 w01 = *(const f16x8*)(b0 + (kt + 1) * 512);
          f16x8 w11 = *(const f16x8*)(b1 + (kt + 1) * 512);
          acc0 = MFMA_F16(a0, w00, acc0); acc1 = MFMA_F16(a0, w10, acc1);
          acc0 = MFMA_F16(a1, w01, acc0); acc1 = MFMA_F16(a1, w11, acc1);
          a0 = na0; a1 = na1;
        }
      }
      {  // epilogue: C/D layout col=lane&15, row=(lane>>4)*4+r
        int rw0 = w * 16 + lq * 4;
        #pragma unroll
        for (int u = 0; u < 2; u++) {
          f32x4 acc = u ? acc1 : acc0;
          int col = (ct0 + u) * 16 + lm;
          float bv = bias[col];
          #pragma unroll
          for (int r = 0; r < 4; r++) {
            int rw = rw0 + r;
            if (type == 0) outF[(size_t)rw * 3072 + col] = acc[r] + bv;
            else           p.ineB[(size_t)rw * 1024 + col] = (f16)geluf(acc[r] + bv);
          }
        }
      }
      __syncthreads();  // protect bS before next pair
    }
    gbar(p.bar, epoch);

    // ======== PHASE B (layer 0: gi0 -> h0n) and PHASE C (layer 1: gi1 -> h1n) ========
    for (int layer = 0; layer < 2; layer++) {
      if (layer == 0 && b == 0 && tid < 128) p.stats[tid] = 0.f;  // zero LN stats for this step
      const int rowg = b & 3, colg = b >> 2;
      const f16* actp = layer ? p.h0B : p.ineB;
      const f16* wp   = layer ? p.wih1P : p.wih0aP;
      {  // stage 16 act rows (32 KB) + 3 gate weight tiles (96 KB)
        const uint4* src = (const uint4*)(actp + (size_t)rowg * 16384);
        for (int i = tid; i < 2048; i += 256) {
          int r = i >> 7, c = i & 127;
          *(uint4*)(actS + r * 1032 + c * 8) = src[i];
        }
        for (int g = 0; g < 3; g++) {
          const uint4* ws4 = (const uint4*)(wp + (size_t)(g * 64 + colg) * 16384);
          uint4* d4 = (uint4*)(bS + (size_t)g * 16384);
          for (int i = tid; i < 2048; i += 256) d4[i] = ws4[i];
        }
      }
      __syncthreads();
      if (w < 3) {  // wave w computes gate w for 16 rows x 16 cols
        f32x4 acc = {0.f, 0.f, 0.f, 0.f};
        const f16* aB = actS + lm * 1032 + lq * 8;
        const f16* bB = bS + (size_t)w * 16384 + l * 8;
        #pragma unroll
        for (int kt = 0; kt < 32; kt++)
          acc = MFMA_F16(*(const f16x8*)(aB + kt * 32), *(const f16x8*)(bB + kt * 512), acc);
        #pragma unroll
        for (int r = 0; r < 4; r++) gateS[w * 256 + (lq * 4 + r) * 16 + lm] = acc[r];
      }
      __syncthreads();
      {  // GRU elementwise: thread = (row i, col j) within 16x16 tile
        int i = tid >> 4, j = tid & 15;
        int row = rowg * 16 + i, hc = colg * 16 + j;
        float g0 = gateS[tid], g1 = gateS[256 + tid], g2 = gateS[512 + tid];
        float ir_, iz_, in_;
        if (layer) {
          ir_ = g0 + p.bih1[hc]; iz_ = g1 + p.bih1[1024 + hc]; in_ = g2 + p.bih1[2048 + hc];
        } else {
          const float* gp = p.gi0p + (size_t)row * 3072;
          ir_ = g0 + gp[hc]; iz_ = g1 + gp[1024 + hc]; in_ = g2 + gp[2048 + hc];
        }
        const float* gh = (layer ? p.gh1 : p.gh0) + (size_t)row * 3072;
        float r_ = sigmf(ir_ + gh[hc]);
        float z_ = sigmf(iz_ + gh[1024 + hc]);
        float n_ = tanhf(in_ + r_ * gh[2048 + hc]);
        float* hF = (layer ? p.h1F : p.h0F) + (size_t)row * 1024 + hc;
        f16*   hB = (layer ? p.h1B : p.h0B) + (size_t)row * 1024 + hc;
        float hn = (1.f - z_) * n_ + z_ * (*hF);
        *hF = hn; *hB = (f16)hn;
        if (layer) {  // LN stats: reduce 16 cols per row, atomically accumulate
          float s1 = hn, s2 = hn * hn;
          #pragma unroll
          for (int d = 1; d < 16; d <<= 1) { s1 += __shfl_xor(s1, d, 16); s2 += __shfl_xor(s2, d, 16); }
          if (j == 0) { atomicAdd(&p.stats[row * 2], s1); atomicAdd(&p.stats[row * 2 + 1], s2); }
        }
      }
      gbar(p.bar, epoch);
    }

    // ======== PHASE D: pred = LN(h1n) @ predW + predB ========
    if (b < 32) {
      const int rowg = b & 3, ct = b >> 2;
      int myrow = rowg * 16 + lm;
      float s1 = p.stats[myrow * 2], s2 = p.stats[myrow * 2 + 1];
      float mean = s1 * 0.0009765625f;
      float var  = s2 * 0.0009765625f - mean * mean;
      float rstd = rsqrtf(var + 1e-5f);
      f32x4 acc = {0.f, 0.f, 0.f, 0.f};
      const f16* hB = p.h1B + (size_t)myrow * 1024 + lq * 8;
      const f16* bB = p.predWP + (size_t)ct * 16384 + l * 8;
      #pragma unroll
      for (int jj = 0; jj < 8; jj++) {  // waves K-split: kt = w*8 + jj
        int kt = w * 8 + jj;
        int k0 = kt * 32 + lq * 8;
        f16x8 hv = *(const f16x8*)(hB + kt * 32);
        f16x8 af;
        #pragma unroll
        for (int e = 0; e < 8; e++)
          af[e] = (f16)((((float)hv[e] - mean) * rstd) * p.ln_g[k0 + e] + p.ln_b[k0 + e]);
        acc = MFMA_F16(af, *(const f16x8*)(bB + kt * 512), acc);
      }
      #pragma unroll
      for (int r = 0; r < 4; r++) gateS[w * 256 + (lq * 4 + r) * 16 + lm] = acc[r];
      __syncthreads();
      {
        int i = tid >> 4, j = tid & 15, col = ct * 16 + j;
        if (col < 126) {
          float v = gateS[tid] + gateS[256 + tid] + gateS[512 + tid] + gateS[768 + tid] + p.predB[col];
          int row = rowg * 16 + i;
          p.predsT[(size_t)t * 8064 + row * 126 + col] = v;
          if (t < 447) p.xcat[((size_t)(t + 1) * 64 + row) * 384 + col] = (f16)v;
        }
      }
    }
    gbar(p.bar, epoch);
  }

  // ======== epilogue: predsT (t,n,m) -> out (n,m,t) ========
  for (int g = b; g < 504; g += 256) {
    int p0 = g * 16;
    for (int t0 = 0; t0 < 448; t0 += 16) {
      int tc = tid >> 4, pp = tid & 15;
      trS[tc * 17 + pp] = p.predsT[(size_t)(t0 + tc) * 8064 + p0 + pp];
      __syncthreads();
      int pp2 = tid >> 4, tc2 = tid & 15;
      p.out[(size_t)(p0 + pp2) * 448 + t0 + tc2] = trS[tc2 * 17 + pp2];
      __syncthreads();
    }
  }
}

// ---------------- host ----------------

extern "C" void kernel_launch(void* const* d_in, const int* in_sizes, int n_in,
                              void* d_out, int out_size, void* d_ws, size_t ws_size,
                              hipStream_t stream) {
  Ptrs p;
  p.aud = (const float*)d_in[0];
  p.mo  = (const float*)d_in[1];
  p.lxm = (const float*)d_in[2];
  p.vid = (const int*)d_in[3];
  p.eps = (const float*)d_in[4];
  p.csi_w0 = (const float*)d_in[5];  p.csi_b0 = (const float*)d_in[6];
  p.csi_w1 = (const float*)d_in[7];  p.csi_b1 = (const float*)d_in[8];
  p.csi_w2 = (const float*)d_in[9];  p.csi_b2 = (const float*)d_in[10];
  p.spk  = (const float*)d_in[11];
  p.mu_w = (const float*)d_in[12];   p.mu_b = (const float*)d_in[13];
  p.lv_w = (const float*)d_in[14];   p.lv_b = (const float*)d_in[15];
  p.embW = (const float*)d_in[16];   p.embB = (const float*)d_in[17];
  p.wih0 = (const float*)d_in[18];   p.whh0 = (const float*)d_in[19];
  p.bih0 = (const float*)d_in[20];   p.bhh0 = (const float*)d_in[21];
  p.wih1 = (const float*)d_in[22];   p.whh1 = (const float*)d_in[23];
  p.bih1 = (const float*)d_in[24];   p.bhh1 = (const float*)d_in[25];
  p.ln_g = (const float*)d_in[26];   p.ln_b = (const float*)d_in[27];
  p.predW = (const float*)d_in[28];  p.predB = (const float*)d_in[29];
  p.out = (float*)d_out;

  char* ws = (char*)d_ws;
  size_t off = 0;
  auto al = [&](size_t bytes) -> void* {
    void* r = (void*)(ws + off);
    off += (bytes + 255) & ~(size_t)255;
    return r;
  };
  p.bar    = (unsigned*)al(256);
  p.stats  = (float*)al(512);
  p.mu5    = (float*)al(640);
  p.lv5    = (float*)al(640);
  p.h0F    = (float*)al(262144);
  p.h1F    = (float*)al(262144);
  p.h0B    = (f16*)al(131072);
  p.h1B    = (f16*)al(131072);
  p.ineB   = (f16*)al(131072);
  p.gh0    = (float*)al(786432);
  p.gh1    = (float*)al(786432);
  p.gi0p   = (float*)al(786432);
  p.x0     = (float*)al(262144);
  p.x1     = (float*)al(262144);
  p.predsT = (float*)al(14450688);
  p.xcat   = (f16*)al(22020096);
  p.whh0P  = (f16*)al(6291456);
  p.whh1P  = (f16*)al(6291456);
  p.wih0aP = (f16*)al(6291456);
  p.wih0bP = (f16*)al(2359296);
  p.wih1P  = (f16*)al(6291456);
  p.embWP  = (f16*)al(786432);
  p.predWP = (f16*)al(262144);

  k_init<<<1, 128, 0, stream>>>(p);

  k_pack<<<dim3(192, 32), 256, 0, stream>>>(p.whh0, p.whh0P, 1024, 0, 3072, 3072);
  k_pack<<<dim3(192, 32), 256, 0, stream>>>(p.whh1, p.whh1P, 1024, 0, 3072, 3072);
  k_pack<<<dim3(192, 32), 256, 0, stream>>>(p.wih0, p.wih0aP, 1024, 0, 3072, 3072);
  k_pack<<<dim3(192, 12), 256, 0, stream>>>(p.wih0, p.wih0bP, 382, 1024, 3072, 3072);
  k_pack<<<dim3(192, 32), 256, 0, stream>>>(p.wih1, p.wih1P, 1024, 0, 3072, 3072);
  k_pack<<<dim3(64, 12), 256, 0, stream>>>(p.embW, p.embWP, 382, 0, 1024, 1024);
  k_pack<<<dim3(8, 32), 256, 0, stream>>>(p.predW, p.predWP, 1024, 0, 126, 126);

  k_csi1<<<256, 256, 0, stream>>>(p);
  k_csi2<<<256, 256, 0, stream>>>(p);
  k_csi3<<<512, 256, 0, stream>>>(p);
  k_style1<<<1, 256, 0, stream>>>(p);
  k_style2<<<3584, 256, 0, stream>>>(p);
  k_aud<<<1792, 256, 0, stream>>>(p);
  k_lxm<<<10752, 256, 0, stream>>>(p);
  k_premo0<<<32, 256, 0, stream>>>(p);

  k_scan<<<256, 256, 136512, stream>>>(p);

  (void)in_sizes; (void)n_in; (void)out_size; (void)ws_size;
}